// Round 17
// baseline (55.822 us; speedup 1.0000x reference)
//
#include <hip/hip_runtime.h>
#include <stdint.h>

#define N_OUT    4096
#define N_IN     4096
#define TOKENS   256
#define N_SPARSE 8388608
#define SPLITK   4
#define BN       64                // GEMM rows of W per block
#define KSPAN    (N_IN / SPLITK)   // 1024 cols per GEMM block
#define KCHUNK   256               // staged sub-tile width

typedef __attribute__((ext_vector_type(8))) short bf16x8;
typedef __attribute__((ext_vector_type(8))) unsigned short u16x8;
typedef __attribute__((ext_vector_type(4))) float f32x4;

__device__ __forceinline__ unsigned short f2bf(float f) {
    union { float f; unsigned u; } v; v.f = f;
    unsigned r = v.u + 0x7fffu + ((v.u >> 16) & 1u);   // RNE
    return (unsigned short)(r >> 16);
}

__device__ __forceinline__ float bf2f(unsigned short u) {
    union { unsigned u; float f; } v; v.u = ((unsigned)u) << 16;
    return v.f;
}

__device__ __forceinline__ void gload_lds16(const void* g, void* l) {
    __builtin_amdgcn_global_load_lds(
        (const __attribute__((address_space(1))) void*)g,
        (__attribute__((address_space(3))) void*)l, 16, 0, 0);
}

// OOB-safe 4-wide load of idx/vals (never reads past N_SPARSE).
__device__ __forceinline__ void ld4(const int* __restrict__ idx,
                                    const float* __restrict__ vals,
                                    int jb, int4& i4, float4& v4) {
    if (jb + 4 <= N_SPARSE) {
        i4 = *(const int4*)(idx + jb);
        v4 = *(const float4*)(vals + jb);
    } else {
        i4 = int4{0, 0, 0, 0}; v4 = float4{0.f, 0.f, 0.f, 0.f};
        #pragma unroll
        for (int e = 0; e < 4; ++e) {
            const int j = jb + e;
            if (j < N_SPARSE) { (&i4.x)[e] = idx[j]; (&v4.x)[e] = vals[j]; }
        }
    }
}

// ---- kernel 1 (merged): x -> MFMA-fragment-layout bf16  +  row_ptr --------
// Fragment layout: element (m,k) of x lives at
//   xs[ ((k>>5)*16 + (m>>4))*512 + ((m&15) | (((k>>3)&3)<<4))*8 + (k&7) ]
// so an A-fragment load in the GEMM is ONE contiguous 16B/lane (1KB/wave).
// row_ptr[r] = lower_bound(idx, r*N_IN), r in [0,4096]; windowed search
// (hypergeometric sigma <= 1449, window 16384 = 11 sigma), GUARDED while.
__global__ void prep(const float* __restrict__ x, const int* __restrict__ idx,
                     unsigned short* __restrict__ xs, int* __restrict__ rp) {
    const int b = blockIdx.x;
    const int t = threadIdx.x;
    if (b < 1024) {
        const int i = (b * 256 + t) * 4;
        const int m = i >> 12;
        const int k = i & 4095;
        const float4 v = *(const float4*)(x + i);
        ushort4 o;
        o.x = f2bf(v.x); o.y = f2bf(v.y); o.z = f2bf(v.z); o.w = f2bf(v.w);
        const int lane = (m & 15) | (((k >> 3) & 3) << 4);
        const int addr = ((k >> 5) * 16 + (m >> 4)) * 512 + lane * 8 + (k & 7);
        *(ushort4*)(xs + addr) = o;     // k..k+3 stay in one 8-elem slot
    } else {
        const int r = (b - 1024) * 256 + t;
        if (r > N_OUT) return;
        const int target = r << 12;
        const int c = r << 11;          // expected position
        int lo = c > 16384 ? c - 16384 : 0;
        int hi = c + 16384 < N_SPARSE ? c + 16384 : N_SPARSE;
        while (lo < hi) {
            const int m = (lo + hi) >> 1;
            if (idx[m] < target) lo = m + 1; else hi = m;
        }
        rp[r] = lo;
    }
}

// ---- kernel 2: build dense bf16 W, one block per row ----------------------
// 4096 blocks x 256 thr (8 co-resident blocks/CU -> statistically continuous
// HBM issue; no intra-block pipelining heroics needed). Per block: zero 8KB
// LDS row, 3-deep preloaded vectorized gather (contiguous per-row stream),
// LDS scatter (2B, ~2-way bank alias = free), 64B/thread vector store out.
__global__ __launch_bounds__(256) void build_w(const int* __restrict__ idx,
                                               const float* __restrict__ vals,
                                               const int* __restrict__ rp,
                                               unsigned short* __restrict__ wb) {
    __shared__ unsigned short row[N_IN];   // 8KB
    const int r = blockIdx.x;
    const int t = threadIdx.x;
    const int base = r << 12;

    {
        const u16x8 z8 = {};
        *(u16x8*)&row[t * 16]     = z8;
        *(u16x8*)&row[t * 16 + 8] = z8;
    }
    const int start = rp[r];
    const int end   = rp[r + 1];
    __syncthreads();

    {
        int jb = (start & ~3) + t * 4;
        int4 ia, ib, ic; float4 va, vb, vc;
        const bool ha = jb < end, hb = jb + 1024 < end, hc = jb + 2048 < end;
        if (ha) ld4(idx, vals, jb,        ia, va);
        if (hb) ld4(idx, vals, jb + 1024, ib, vb);
        if (hc) ld4(idx, vals, jb + 2048, ic, vc);
        #pragma unroll
        for (int e = 0; e < 4; ++e) {
            const int j = jb + e;
            if (j >= start && j < end) row[(&ia.x)[e] - base] = f2bf((&va.x)[e]);
        }
        if (hb) {
            #pragma unroll
            for (int e = 0; e < 4; ++e) {
                const int j = jb + 1024 + e;
                if (j < end) row[(&ib.x)[e] - base] = f2bf((&vb.x)[e]);
            }
        }
        if (hc) {
            #pragma unroll
            for (int e = 0; e < 4; ++e) {
                const int j = jb + 2048 + e;
                if (j < end) row[(&ic.x)[e] - base] = f2bf((&vc.x)[e]);
            }
        }
        // tail (span > 3072: ~never; guarded for safety)
        for (jb += 3072; jb < end; jb += 1024) {
            int4 i4; float4 v4;
            ld4(idx, vals, jb, i4, v4);
            #pragma unroll
            for (int e = 0; e < 4; ++e) {
                const int j = jb + e;
                if (j < end) row[(&i4.x)[e] - base] = f2bf((&v4.x)[e]);
            }
        }
    }
    __syncthreads();

    unsigned short* wo = wb + (size_t)base + t * 16;
    *(u16x8*)wo       = *(const u16x8*)&row[t * 16];
    *(u16x8*)(wo + 8) = *(const u16x8*)&row[t * 16 + 8];
}

// ---- kernel 3: bf16 MFMA GEMM from materialized W (L3-resident) -----------
// Block (bn, bz): W rows bn*64..+63, cols bz*1024..+1023 in 4 staged chunks.
// B staged via global_load_lds (linear LDS dest, XOR-swizzled SOURCE slot;
// read applies same XOR -> conflict-free ds_read_b128). A fragments straight
// from pre-fragmented L2-resident xs. Double-buffered Bs; stage(t+1) issued
// after afr(t) loads so MFMA's vmcnt wait never drains the stage. bf16 part.
__global__ __launch_bounds__(512) void gemm_bt(
        const unsigned short* __restrict__ xs,
        const unsigned short* __restrict__ wb,
        unsigned short* __restrict__ part)       // SPLITK x 256 x 4096 bf16
{
    __shared__ short Bs[2][BN * KCHUNK];  // 2 x 32KB

    const int tid = threadIdx.x;
    const int l   = tid & 63;
    const int w   = tid >> 6;            // 0..7
    const int bn  = blockIdx.x;          // 0..63
    const int bz  = blockIdx.y;          // 0..3

    // stage addressing: round rnd covers rows rnd*16 + (tid>>5), slot tid&31
    const int srow  = tid >> 5;          // row offset within 16-row group
    const int sslot = tid & 31;          // 16B slot 0..31
    const unsigned short* wbase = wb + (size_t)(bn * BN) * N_IN + bz * KSPAN;

#define STAGE(tt, bb) do { \
        _Pragma("unroll") \
        for (int rnd = 0; rnd < 4; ++rnd) { \
            const int row = rnd * 16 + srow; \
            gload_lds16(wbase + (size_t)row * N_IN + (tt) * KCHUNK \
                              + ((sslot ^ (row & 7)) * 8), \
                        &Bs[bb][rnd * 4096 + tid * 8]); \
        } } while (0)

    STAGE(0, 0);
    __syncthreads();   // drains stage(0)

    const int lr  = l & 15;
    const int lkg = l >> 4;              // 0..3
    f32x4 acc[2][4] = {};

    #pragma unroll
    for (int t = 0; t < 4; ++t) {
        const int cur = t & 1;
        const int seg = bz * 4 + t;

        // afr loads FIRST (oldest) so MFMA's counted vmcnt leaves the
        // stage(t+1) burst in flight.
        bf16x8 afr[16];
        {
            const unsigned short* ax = xs + (size_t)(seg * 128) * 512 + l * 8;
            #pragma unroll
            for (int q = 0; q < 16; ++q)
                afr[q] = *(const bf16x8*)(ax + (size_t)((q >> 1) * 16 + w * 2 + (q & 1)) * 512);
        }
        if (t + 1 < 4) STAGE(t + 1, cur ^ 1);

        {
            const short* bsc = &Bs[cur][0];
            #pragma unroll
            for (int kk = 0; kk < KCHUNK / 32; ++kk) {   // 8 steps of K=32
                bf16x8 bfr[4];
                #pragma unroll
                for (int i = 0; i < 4; ++i) {
                    const int n    = i * 16 + lr;
                    const int slot = (kk * 4 + lkg) ^ (n & 7);
                    bfr[i] = *(const bf16x8*)&bsc[n * KCHUNK + slot * 8];
                }
                #pragma unroll
                for (int mi = 0; mi < 2; ++mi)
                    #pragma unroll
                    for (int ni = 0; ni < 4; ++ni)
                        acc[mi][ni] = __builtin_amdgcn_mfma_f32_16x16x32_bf16(
                                          afr[kk * 2 + mi], bfr[ni], acc[mi][ni], 0, 0, 0);
            }
        }
        __syncthreads();   // stage(t+1) landed under MFMA(t); buffers swap
    }
#undef STAGE

    // --- epilogue: bf16 partials, C/D layout col=lane&15, row=(l>>4)*4+reg --
    unsigned short* po = part + (size_t)bz * (TOKENS * N_OUT) + (size_t)bn * BN;
    #pragma unroll
    for (int mi = 0; mi < 2; ++mi)
        #pragma unroll
        for (int r = 0; r < 4; ++r) {
            const int m = w * 32 + mi * 16 + lkg * 4 + r;
            #pragma unroll
            for (int ni = 0; ni < 4; ++ni) {
                const int n = ni * 16 + lr;
                po[(size_t)m * N_OUT + n] = f2bf(acc[mi][ni][r]);
            }
        }
}

// ---- kernel 4: sum bf16 split-K partials -> f32 out -----------------------
__global__ void reduce_k(const unsigned short* __restrict__ part, float* __restrict__ out) {
    const int i = (blockIdx.x * 256 + threadIdx.x) * 8;
    float a[8] = {};
    for (int z = 0; z < SPLITK; ++z) {
        const u16x8 p = *(const u16x8*)(part + (size_t)z * (TOKENS * N_OUT) + i);
        #pragma unroll
        for (int j = 0; j < 8; ++j) a[j] += bf2f((unsigned short)p[j]);
    }
    float4 o0 = { a[0], a[1], a[2], a[3] };
    float4 o1 = { a[4], a[5], a[6], a[7] };
    *(float4*)(out + i)     = o0;
    *(float4*)(out + i + 4) = o1;
}

// ---- fallback (ws too small): per-output-row CSR, fp32 -------------------
__global__ void fallback_rowcsr(const float* __restrict__ x, const float* __restrict__ vals,
                                const int* __restrict__ idx, float* __restrict__ out) {
    const int o = blockIdx.x;
    const int t = threadIdx.x;
    __shared__ int   scol[256];
    __shared__ float sval[256];

    int lo = 0, hi = N_SPARSE;
    const int target = o * N_IN;
    while (lo < hi) { int m = (lo + hi) >> 1; if (idx[m] < target) lo = m + 1; else hi = m; }
    const int start = lo;
    hi = N_SPARSE;
    const int target2 = target + N_IN;
    while (lo < hi) { int m = (lo + hi) >> 1; if (idx[m] < target2) lo = m + 1; else hi = m; }
    const int end = lo;

    float acc = 0.f;
    const float* xr = x + (size_t)t * N_IN;
    for (int base = start; base < end; base += 256) {
        const int k = base + t;
        if (k < end) { scol[t] = idx[k] - target; sval[t] = vals[k]; }
        __syncthreads();
        const int cnt = min(256, end - base);
        for (int j = 0; j < cnt; ++j) acc += sval[j] * xr[scol[j]];
        __syncthreads();
    }
    out[(size_t)t * N_OUT + o] = acc;
}

extern "C" void kernel_launch(void* const* d_in, const int* in_sizes, int n_in,
                              void* d_out, int out_size, void* d_ws, size_t ws_size,
                              hipStream_t stream) {
    const float* x    = (const float*)d_in[0];
    const float* vals = (const float*)d_in[1];
    const int*   idx  = (const int*)d_in[2];
    float* out = (float*)d_out;

    const size_t part_bytes = (size_t)SPLITK * TOKENS * N_OUT * 2;   // 8 MB
    const size_t xs_bytes   = (size_t)TOKENS * N_IN * 2;             // 2 MB
    const size_t wb_bytes   = (size_t)N_OUT * N_IN * 2;              // 32 MB
    const size_t rp_bytes   = (size_t)(N_OUT + 1) * 4;
    const size_t need = part_bytes + xs_bytes + wb_bytes + rp_bytes; // ~42.3 MB

    if (ws_size >= need) {
        unsigned short* part = (unsigned short*)d_ws;
        unsigned short* xs   = (unsigned short*)((char*)d_ws + part_bytes);
        unsigned short* wb   = (unsigned short*)((char*)d_ws + part_bytes + xs_bytes);
        int*            rp   = (int*)((char*)d_ws + part_bytes + xs_bytes + wb_bytes);

        prep<<<1024 + 17, 256, 0, stream>>>(x, idx, xs, rp);
        build_w<<<N_OUT, 256, 0, stream>>>(idx, vals, rp, wb);
        dim3 grid(N_OUT / BN, SPLITK);
        gemm_bt<<<grid, 512, 0, stream>>>(xs, wb, part);
        reduce_k<<<(TOKENS * N_OUT) / 2048, 256, 0, stream>>>(part, out);
    } else {
        fallback_rowcsr<<<N_OUT, TOKENS, 0, stream>>>(x, vals, idx, out);
    }
}

// Round 18
// 55.769 us; speedup vs baseline: 1.0009x; 1.0009x over previous
//
#include <hip/hip_runtime.h>
#include <stdint.h>

#define N_OUT    4096
#define N_IN     4096
#define TOKENS   256
#define N_SPARSE 8388608
#define SPLITK   4
#define BN       64                // GEMM rows of W per block
#define KSPAN    (N_IN / SPLITK)   // 1024 cols per GEMM block
#define KCHUNK   256               // staged sub-tile width

typedef __attribute__((ext_vector_type(8))) short bf16x8;
typedef __attribute__((ext_vector_type(8))) unsigned short u16x8;
typedef __attribute__((ext_vector_type(4))) float f32x4;

__device__ __forceinline__ unsigned short f2bf(float f) {
    union { float f; unsigned u; } v; v.f = f;
    unsigned r = v.u + 0x7fffu + ((v.u >> 16) & 1u);   // RNE
    return (unsigned short)(r >> 16);
}

__device__ __forceinline__ float bf2f(unsigned short u) {
    union { unsigned u; float f; } v; v.u = ((unsigned)u) << 16;
    return v.f;
}

__device__ __forceinline__ void gload_lds16(const void* g, void* l) {
    __builtin_amdgcn_global_load_lds(
        (const __attribute__((address_space(1))) void*)g,
        (__attribute__((address_space(3))) void*)l, 16, 0, 0);
}

// OOB-safe 4-wide load of idx/vals (never reads past N_SPARSE).
__device__ __forceinline__ void ld4(const int* __restrict__ idx,
                                    const float* __restrict__ vals,
                                    int jb, int4& i4, float4& v4) {
    if (jb + 4 <= N_SPARSE) {
        i4 = *(const int4*)(idx + jb);
        v4 = *(const float4*)(vals + jb);
    } else {
        i4 = int4{0, 0, 0, 0}; v4 = float4{0.f, 0.f, 0.f, 0.f};
        #pragma unroll
        for (int e = 0; e < 4; ++e) {
            const int j = jb + e;
            if (j < N_SPARSE) { (&i4.x)[e] = idx[j]; (&v4.x)[e] = vals[j]; }
        }
    }
}

// ---- kernel 1 (merged): x -> MFMA-fragment-layout bf16  +  row_ptr --------
// Fragment layout: element (m,k) of x lives at
//   xs[ ((k>>5)*16 + (m>>4))*512 + ((m&15) | (((k>>3)&3)<<4))*8 + (k&7) ]
// so an A-fragment load in the GEMM is ONE contiguous 16B/lane (1KB/wave).
// row_ptr[r] = lower_bound(idx, r*N_IN), r in [0,4096]; windowed search
// (hypergeometric sigma <= 1449, window 16384 = 11 sigma), GUARDED while.
__global__ void prep(const float* __restrict__ x, const int* __restrict__ idx,
                     unsigned short* __restrict__ xs, int* __restrict__ rp) {
    const int b = blockIdx.x;
    const int t = threadIdx.x;
    if (b < 1024) {
        const int i = (b * 256 + t) * 4;
        const int m = i >> 12;
        const int k = i & 4095;
        const float4 v = *(const float4*)(x + i);
        ushort4 o;
        o.x = f2bf(v.x); o.y = f2bf(v.y); o.z = f2bf(v.z); o.w = f2bf(v.w);
        const int lane = (m & 15) | (((k >> 3) & 3) << 4);
        const int addr = ((k >> 5) * 16 + (m >> 4)) * 512 + lane * 8 + (k & 7);
        *(ushort4*)(xs + addr) = o;     // k..k+3 stay in one 8-elem slot
    } else {
        const int r = (b - 1024) * 256 + t;
        if (r > N_OUT) return;
        const int target = r << 12;
        const int c = r << 11;          // expected position
        int lo = c > 16384 ? c - 16384 : 0;
        int hi = c + 16384 < N_SPARSE ? c + 16384 : N_SPARSE;
        while (lo < hi) {
            const int m = (lo + hi) >> 1;
            if (idx[m] < target) lo = m + 1; else hi = m;
        }
        rp[r] = lo;
    }
}

// ---- kernel 2: build dense bf16 W, one block per row ----------------------
// 4096 blocks x 256 thr (8 co-resident blocks/CU -> statistically continuous
// HBM issue; no intra-block pipelining heroics needed). Per block: zero 8KB
// LDS row, 3-deep preloaded vectorized gather (contiguous per-row stream),
// LDS scatter (2B, ~2-way bank alias = free), 64B/thread vector store out.
__global__ __launch_bounds__(256) void build_w(const int* __restrict__ idx,
                                               const float* __restrict__ vals,
                                               const int* __restrict__ rp,
                                               unsigned short* __restrict__ wb) {
    __shared__ unsigned short row[N_IN];   // 8KB
    const int r = blockIdx.x;
    const int t = threadIdx.x;
    const int base = r << 12;

    {
        const u16x8 z8 = {};
        *(u16x8*)&row[t * 16]     = z8;
        *(u16x8*)&row[t * 16 + 8] = z8;
    }
    const int start = rp[r];
    const int end   = rp[r + 1];
    __syncthreads();

    {
        int jb = (start & ~3) + t * 4;
        int4 ia, ib, ic; float4 va, vb, vc;
        const bool ha = jb < end, hb = jb + 1024 < end, hc = jb + 2048 < end;
        if (ha) ld4(idx, vals, jb,        ia, va);
        if (hb) ld4(idx, vals, jb + 1024, ib, vb);
        if (hc) ld4(idx, vals, jb + 2048, ic, vc);
        #pragma unroll
        for (int e = 0; e < 4; ++e) {
            const int j = jb + e;
            if (j >= start && j < end) row[(&ia.x)[e] - base] = f2bf((&va.x)[e]);
        }
        if (hb) {
            #pragma unroll
            for (int e = 0; e < 4; ++e) {
                const int j = jb + 1024 + e;
                if (j < end) row[(&ib.x)[e] - base] = f2bf((&vb.x)[e]);
            }
        }
        if (hc) {
            #pragma unroll
            for (int e = 0; e < 4; ++e) {
                const int j = jb + 2048 + e;
                if (j < end) row[(&ic.x)[e] - base] = f2bf((&vc.x)[e]);
            }
        }
        // tail (span > 3072: ~never; guarded for safety)
        for (jb += 3072; jb < end; jb += 1024) {
            int4 i4; float4 v4;
            ld4(idx, vals, jb, i4, v4);
            #pragma unroll
            for (int e = 0; e < 4; ++e) {
                const int j = jb + e;
                if (j < end) row[(&i4.x)[e] - base] = f2bf((&v4.x)[e]);
            }
        }
    }
    __syncthreads();

    unsigned short* wo = wb + (size_t)base + t * 16;
    *(u16x8*)wo       = *(const u16x8*)&row[t * 16];
    *(u16x8*)(wo + 8) = *(const u16x8*)&row[t * 16 + 8];
}

// ---- kernel 3: bf16 MFMA GEMM from materialized W (L3-resident) -----------
// Block (bn, bz): W rows bn*64..+63, cols bz*1024..+1023 in 4 staged chunks.
// B staged via global_load_lds (linear LDS dest, XOR-swizzled SOURCE slot;
// read applies same XOR -> conflict-free ds_read_b128). A fragments straight
// from pre-fragmented L2-resident xs. Double-buffered Bs; stage(t+1) issued
// after afr(t) loads so MFMA's vmcnt wait never drains the stage. bf16 part.
__global__ __launch_bounds__(512) void gemm_bt(
        const unsigned short* __restrict__ xs,
        const unsigned short* __restrict__ wb,
        unsigned short* __restrict__ part)       // SPLITK x 256 x 4096 bf16
{
    __shared__ short Bs[2][BN * KCHUNK];  // 2 x 32KB

    const int tid = threadIdx.x;
    const int l   = tid & 63;
    const int w   = tid >> 6;            // 0..7
    const int bn  = blockIdx.x;          // 0..63
    const int bz  = blockIdx.y;          // 0..3

    // stage addressing: round rnd covers rows rnd*16 + (tid>>5), slot tid&31
    const int srow  = tid >> 5;          // row offset within 16-row group
    const int sslot = tid & 31;          // 16B slot 0..31
    const unsigned short* wbase = wb + (size_t)(bn * BN) * N_IN + bz * KSPAN;

#define STAGE(tt, bb) do { \
        _Pragma("unroll") \
        for (int rnd = 0; rnd < 4; ++rnd) { \
            const int row = rnd * 16 + srow; \
            gload_lds16(wbase + (size_t)row * N_IN + (tt) * KCHUNK \
                              + ((sslot ^ (row & 7)) * 8), \
                        &Bs[bb][rnd * 4096 + tid * 8]); \
        } } while (0)

    STAGE(0, 0);
    __syncthreads();   // drains stage(0)

    const int lr  = l & 15;
    const int lkg = l >> 4;              // 0..3
    f32x4 acc[2][4] = {};

    #pragma unroll
    for (int t = 0; t < 4; ++t) {
        const int cur = t & 1;
        const int seg = bz * 4 + t;

        // afr loads FIRST (oldest) so MFMA's counted vmcnt leaves the
        // stage(t+1) burst in flight.
        bf16x8 afr[16];
        {
            const unsigned short* ax = xs + (size_t)(seg * 128) * 512 + l * 8;
            #pragma unroll
            for (int q = 0; q < 16; ++q)
                afr[q] = *(const bf16x8*)(ax + (size_t)((q >> 1) * 16 + w * 2 + (q & 1)) * 512);
        }
        if (t + 1 < 4) STAGE(t + 1, cur ^ 1);

        {
            const short* bsc = &Bs[cur][0];
            #pragma unroll
            for (int kk = 0; kk < KCHUNK / 32; ++kk) {   // 8 steps of K=32
                bf16x8 bfr[4];
                #pragma unroll
                for (int i = 0; i < 4; ++i) {
                    const int n    = i * 16 + lr;
                    const int slot = (kk * 4 + lkg) ^ (n & 7);
                    bfr[i] = *(const bf16x8*)&bsc[n * KCHUNK + slot * 8];
                }
                #pragma unroll
                for (int mi = 0; mi < 2; ++mi)
                    #pragma unroll
                    for (int ni = 0; ni < 4; ++ni)
                        acc[mi][ni] = __builtin_amdgcn_mfma_f32_16x16x32_bf16(
                                          afr[kk * 2 + mi], bfr[ni], acc[mi][ni], 0, 0, 0);
            }
        }
        __syncthreads();   // stage(t+1) landed under MFMA(t); buffers swap
    }
#undef STAGE

    // --- epilogue: bf16 partials, C/D layout col=lane&15, row=(l>>4)*4+reg --
    unsigned short* po = part + (size_t)bz * (TOKENS * N_OUT) + (size_t)bn * BN;
    #pragma unroll
    for (int mi = 0; mi < 2; ++mi)
        #pragma unroll
        for (int r = 0; r < 4; ++r) {
            const int m = w * 32 + mi * 16 + lkg * 4 + r;
            #pragma unroll
            for (int ni = 0; ni < 4; ++ni) {
                const int n = ni * 16 + lr;
                po[(size_t)m * N_OUT + n] = f2bf(acc[mi][ni][r]);
            }
        }
}

// ---- kernel 4: sum bf16 split-K partials -> f32 out -----------------------
__global__ void reduce_k(const unsigned short* __restrict__ part, float* __restrict__ out) {
    const int i = (blockIdx.x * 256 + threadIdx.x) * 8;
    float a[8] = {};
    for (int z = 0; z < SPLITK; ++z) {
        const u16x8 p = *(const u16x8*)(part + (size_t)z * (TOKENS * N_OUT) + i);
        #pragma unroll
        for (int j = 0; j < 8; ++j) a[j] += bf2f((unsigned short)p[j]);
    }
    float4 o0 = { a[0], a[1], a[2], a[3] };
    float4 o1 = { a[4], a[5], a[6], a[7] };
    *(float4*)(out + i)     = o0;
    *(float4*)(out + i + 4) = o1;
}

// ---- fallback (ws too small): per-output-row CSR, fp32 -------------------
__global__ void fallback_rowcsr(const float* __restrict__ x, const float* __restrict__ vals,
                                const int* __restrict__ idx, float* __restrict__ out) {
    const int o = blockIdx.x;
    const int t = threadIdx.x;
    __shared__ int   scol[256];
    __shared__ float sval[256];

    int lo = 0, hi = N_SPARSE;
    const int target = o * N_IN;
    while (lo < hi) { int m = (lo + hi) >> 1; if (idx[m] < target) lo = m + 1; else hi = m; }
    const int start = lo;
    hi = N_SPARSE;
    const int target2 = target + N_IN;
    while (lo < hi) { int m = (lo + hi) >> 1; if (idx[m] < target2) lo = m + 1; else hi = m; }
    const int end = lo;

    float acc = 0.f;
    const float* xr = x + (size_t)t * N_IN;
    for (int base = start; base < end; base += 256) {
        const int k = base + t;
        if (k < end) { scol[t] = idx[k] - target; sval[t] = vals[k]; }
        __syncthreads();
        const int cnt = min(256, end - base);
        for (int j = 0; j < cnt; ++j) acc += sval[j] * xr[scol[j]];
        __syncthreads();
    }
    out[(size_t)t * N_OUT + o] = acc;
}

extern "C" void kernel_launch(void* const* d_in, const int* in_sizes, int n_in,
                              void* d_out, int out_size, void* d_ws, size_t ws_size,
                              hipStream_t stream) {
    const float* x    = (const float*)d_in[0];
    const float* vals = (const float*)d_in[1];
    const int*   idx  = (const int*)d_in[2];
    float* out = (float*)d_out;

    const size_t part_bytes = (size_t)SPLITK * TOKENS * N_OUT * 2;   // 8 MB
    const size_t xs_bytes   = (size_t)TOKENS * N_IN * 2;             // 2 MB
    const size_t wb_bytes   = (size_t)N_OUT * N_IN * 2;              // 32 MB
    const size_t rp_bytes   = (size_t)(N_OUT + 1) * 4;
    const size_t need = part_bytes + xs_bytes + wb_bytes + rp_bytes; // ~42.3 MB

    if (ws_size >= need) {
        unsigned short* part = (unsigned short*)d_ws;
        unsigned short* xs   = (unsigned short*)((char*)d_ws + part_bytes);
        unsigned short* wb   = (unsigned short*)((char*)d_ws + part_bytes + xs_bytes);
        int*            rp   = (int*)((char*)d_ws + part_bytes + xs_bytes + wb_bytes);

        prep<<<1024 + 17, 256, 0, stream>>>(x, idx, xs, rp);
        build_w<<<N_OUT, 256, 0, stream>>>(idx, vals, rp, wb);
        dim3 grid(N_OUT / BN, SPLITK);
        gemm_bt<<<grid, 512, 0, stream>>>(xs, wb, part);
        reduce_k<<<(TOKENS * N_OUT) / 2048, 256, 0, stream>>>(part, out);
    } else {
        fallback_rowcsr<<<N_OUT, TOKENS, 0, stream>>>(x, vals, idx, out);
    }
}